// Round 6
// baseline (348.639 us; speedup 1.0000x reference)
//
#include <hip/hip_runtime.h>
#include <hip/hip_bf16.h>
#include <cstdint>
#include <cstddef>

// Shapes (fixed): B=4, C=512, H=W=64, N=4096, td=512. Inputs/outputs fp32.
// Compute in bf16 MFMA (GEMMs) / fp32 VALU (convs, attention).
//
// ws layout (bytes; total ~114.6 MiB):
//   w_qkv_bf  1,572,864 | w_proj_bf 1,048,576 | vk 147,456 |
//   x_t (4,4096,512) bf16 16,777,216 | qkv 50,331,648 | agg 50,331,648
//
// attn is stored head-chunk-transposed over the dead v-rows of qkv/agg.

typedef __hip_bfloat16 bf16;
typedef __attribute__((ext_vector_type(8))) short short8;
typedef __attribute__((ext_vector_type(4))) float f32x4;

__device__ __forceinline__ float b2f(bf16 v) { return __bfloat162float(v); }
__device__ __forceinline__ bf16 f2b(float v) { return __float2bfloat16(v); }

__device__ __forceinline__ void async16(void* lds_base, const void* gaddr) {
    __builtin_amdgcn_global_load_lds(
        (const __attribute__((address_space(1))) unsigned int*)gaddr,
        (__attribute__((address_space(3))) unsigned int*)lds_base,
        16, 0, 0);
}

// ---- weight fp32 -> bf16 ----
__global__ __launch_bounds__(256) void convert_kernel(
    const float* __restrict__ src, bf16* __restrict__ dst, int n)
{
    int i = blockIdx.x * 256 + threadIdx.x;
    if (i < n) dst[i] = f2b(src[i]);
}

// ---- x (4,512,4096) fp32 -> x_t (4,4096,512) bf16 ----
__global__ __launch_bounds__(256) void transpose_x_kernel(
    const float* __restrict__ x, bf16* __restrict__ x_t)
{
    __shared__ bf16 tile[32][33];
    const int b = blockIdx.z;
    const int c0 = blockIdx.y * 32;
    const int n0 = blockIdx.x * 32;
    const int tx = threadIdx.x & 31, ty = threadIdx.x >> 5;  // 32x8
    #pragma unroll
    for (int i = 0; i < 32; i += 8)
        tile[ty + i][tx] = f2b(x[((size_t)b * 512 + c0 + ty + i) * 4096 + n0 + tx]);
    __syncthreads();
    #pragma unroll
    for (int i = 0; i < 32; i += 8)
        x_t[((size_t)b * 4096 + n0 + ty + i) * 512 + c0 + tx] = tile[tx][ty + i];
}

// ---- MFMA GEMM, m97 structure: 128x128 tile, BK=32, 4 waves, 64x64/wave ----
template <bool PROJ>
__global__ __launch_bounds__(256) void mfma_gemm_kernel(
    const bf16* __restrict__ A, const bf16* __restrict__ xt_or_qkv,
    const bf16* __restrict__ agg, const float* __restrict__ X,
    void* __restrict__ Cout, int M, int K)
{
    constexpr int N = 4096;
    const int b = blockIdx.z;
    const int m_blk = blockIdx.y * 128;
    const int n_blk = blockIdx.x * 128;

    __shared__ short As[128 * 32];
    __shared__ short Bs[128 * 32];

    const int tid = threadIdx.x;
    const int lane = tid & 63, wave = tid >> 6;
    const int wm = (wave >> 1) * 64, wn = (wave & 1) * 64;
    const int fm = lane & 15, fq = lane >> 4;

    f32x4 acc[4][4] = {};

    const short* Ag = (const short*)A;
    const short* Btg = PROJ ? nullptr
        : (const short*)(xt_or_qkv + (size_t)b * N * 512);

    for (int k0 = 0; k0 < K; k0 += 32) {
        #pragma unroll
        for (int t0 = 0; t0 < 2; ++t0) {
            int t = wave + t0 * 4;
            int row = m_blk + t * 16 + (lane >> 2);
            int col = k0 + (lane & 3) * 8;
            async16(&As[t * 512], Ag + (size_t)row * K + col);
        }
        #pragma unroll
        for (int t0 = 0; t0 < 2; ++t0) {
            int t = wave + t0 * 4;
            int n = n_blk + t * 16 + (lane >> 2);
            if (!PROJ) {
                int col = k0 + (lane & 3) * 8;
                async16(&Bs[t * 512], Btg + (size_t)n * 512 + col);
            } else {
                int h = (k0 >> 3) + (lane & 3);
                const bf16* chunk = (h < 64 ? xt_or_qkv : agg) +
                    ((size_t)b * 1536 + (size_t)(h & 63) * 24 + 16) * 4096;
                async16(&Bs[t * 512], chunk + (size_t)n * 8);
            }
        }
        __syncthreads();

        short8 af[4], bfv[4];
        #pragma unroll
        for (int i = 0; i < 4; ++i)
            af[i] = *(const short8*)&As[(wm + i * 16 + fm) * 32 + fq * 8];
        #pragma unroll
        for (int j = 0; j < 4; ++j)
            bfv[j] = *(const short8*)&Bs[(wn + j * 16 + fm) * 32 + fq * 8];
        #pragma unroll
        for (int i = 0; i < 4; ++i)
            #pragma unroll
            for (int j = 0; j < 4; ++j)
                acc[i][j] = __builtin_amdgcn_mfma_f32_16x16x32_bf16(
                    af[i], bfv[j], acc[i][j], 0, 0, 0);
        __syncthreads();
    }

    if (!PROJ) {
        bf16* Cb = (bf16*)Cout + (size_t)b * M * N;
        #pragma unroll
        for (int i = 0; i < 4; ++i)
            #pragma unroll
            for (int j = 0; j < 4; ++j) {
                int n = n_blk + wn + j * 16 + fm;
                #pragma unroll
                for (int r = 0; r < 4; ++r) {
                    int m = m_blk + wm + i * 16 + fq * 4 + r;
                    Cb[(size_t)m * N + n] = f2b(acc[i][j][r]);
                }
            }
    } else {
        float* Ob = (float*)Cout + (size_t)b * M * N;
        const float* Xb = X + (size_t)b * M * N;
        #pragma unroll
        for (int i = 0; i < 4; ++i)
            #pragma unroll
            for (int j = 0; j < 4; ++j) {
                int n = n_blk + wn + j * 16 + fm;
                #pragma unroll
                for (int r = 0; r < 4; ++r) {
                    int m = m_blk + wm + i * 16 + fq * 4 + r;
                    size_t off = (size_t)m * N + n;
                    Ob[off] = acc[i][j][r] + Xb[off];
                }
            }
    }
}

// ---- fused depthwise 5x5 (pad 2) + grouped pointwise (8->8), v2 ----
// Block = (b, g, 32-row strip). Lane = column (64 wide). Each wave computes
// an 8-row x 64-col strip via a 12-row sliding window per channel.
// LDS: 8 ch x 36 rows x 68 cols fp32 (halo = 2 vert rows + 2 cols each side).
__global__ __launch_bounds__(256) void dwpw_kernel(
    const bf16* __restrict__ qkv, const float* __restrict__ w_dw,
    const float* __restrict__ w_pw, bf16* __restrict__ agg)
{
    const int bg = blockIdx.z;       // 0..767
    const int b = bg / 192;
    const int g = bg % 192;
    const int y0 = blockIdx.y * 32;  // 0 or 32

    __shared__ float s_in[8][36][68];
    __shared__ float s_wdw[8][25];
    __shared__ float s_wpw[8][8];    // [o][i]

    const int tid = threadIdx.x;
    const int lane = tid & 63, wave = tid >> 6;

    if (tid < 200) {
        int c = tid / 25, k = tid % 25;
        s_wdw[c][k] = w_dw[(size_t)(g * 8 + c) * 25 + k];
    }
    if (tid < 64) {
        s_wpw[tid >> 3][tid & 7] = w_pw[(size_t)(g * 8 + (tid >> 3)) * 8 + (tid & 7)];
    }

    const size_t chan_base = ((size_t)b * 1536 + g * 8) * 4096;

    // Load halo tile: s_in[c][r][col] = image(y0 + r - 2, col - 2), 0 outside.
    #pragma unroll 2
    for (int c = 0; c < 8; ++c) {
        const bf16* src = qkv + chan_base + (size_t)c * 4096;
        for (int r = wave; r < 36; r += 4) {
            int y = y0 + r - 2;
            bool yok = (y >= 0 && y < 64);
            {
                int x = lane - 2;
                float v = 0.f;
                if (yok && x >= 0) v = b2f(src[y * 64 + x]);   // x<62<64 always
                s_in[c][r][lane] = v;
            }
            if (lane < 4) {
                int x = lane + 62;
                float v = 0.f;
                if (yok && x < 64) v = b2f(src[y * 64 + x]);
                s_in[c][r][lane + 64] = v;
            }
        }
    }
    __syncthreads();

    const int ry0 = wave * 8;      // this wave's output-row offset in tile
    float outv[8][8];              // [out_ch][row]
    #pragma unroll
    for (int o = 0; o < 8; ++o)
        #pragma unroll
        for (int r = 0; r < 8; ++r) outv[o][r] = 0.f;

    for (int c = 0; c < 8; ++c) {
        float wr[25];
        #pragma unroll
        for (int k = 0; k < 25; ++k) wr[k] = s_wdw[c][k];

        float dwv[8] = {};
        // input (LDS) rows ry0 .. ry0+11 feed output rows ry0..ry0+7
        #pragma unroll
        for (int ir = 0; ir < 12; ++ir) {
            int sr = ry0 + ir;
            float v0 = s_in[c][sr][lane + 0];
            float v1 = s_in[c][sr][lane + 1];
            float v2 = s_in[c][sr][lane + 2];
            float v3 = s_in[c][sr][lane + 3];
            float v4 = s_in[c][sr][lane + 4];
            #pragma unroll
            for (int i = 0; i < 5; ++i) {
                int o = ir - i;                 // compile-time
                if (o >= 0 && o < 8) {
                    float dot = wr[i * 5 + 0] * v0 + wr[i * 5 + 1] * v1 +
                                wr[i * 5 + 2] * v2 + wr[i * 5 + 3] * v3 +
                                wr[i * 5 + 4] * v4;
                    dwv[o] += dot;
                }
            }
        }
        float wp[8];
        #pragma unroll
        for (int o = 0; o < 8; ++o) wp[o] = s_wpw[o][c];
        #pragma unroll
        for (int o = 0; o < 8; ++o)
            #pragma unroll
            for (int r = 0; r < 8; ++r)
                outv[o][r] += dwv[r] * wp[o];
    }

    #pragma unroll
    for (int o = 0; o < 8; ++o) {
        bf16* dst = agg + chan_base + (size_t)o * 4096;
        #pragma unroll
        for (int r = 0; r < 8; ++r)
            dst[(size_t)(y0 + ry0 + r) * 64 + lane] = f2b(outv[o][r]);
    }
}

// ---- vk[bh,d,e] = sum_n v[d,n]*relu(k[e,n]); row d=8 = sum relu(k) ----
__global__ __launch_bounds__(256) void vk_kernel(
    const bf16* __restrict__ qkv, const bf16* __restrict__ agg,
    float* __restrict__ vk)
{
    const int bh = blockIdx.x;   // 0..511
    const int b = bh >> 7;
    const int h = bh & 127;
    const bf16* base = (h < 64)
        ? (qkv + ((size_t)b * 1536 + h * 24) * 4096)
        : (agg + ((size_t)b * 1536 + (h - 64) * 24) * 4096);

    const int tid = threadIdx.x;
    float acc[9][8] = {};

    for (int n = tid; n < 4096; n += 256) {
        float kv[8], vv[8];
        #pragma unroll
        for (int e = 0; e < 8; ++e) kv[e] = fmaxf(b2f(base[(size_t)(8 + e) * 4096 + n]), 0.f);
        #pragma unroll
        for (int d = 0; d < 8; ++d) vv[d] = b2f(base[(size_t)(16 + d) * 4096 + n]);
        #pragma unroll
        for (int d = 0; d < 8; ++d)
            #pragma unroll
            for (int e = 0; e < 8; ++e)
                acc[d][e] += vv[d] * kv[e];
        #pragma unroll
        for (int e = 0; e < 8; ++e) acc[8][e] += kv[e];
    }

    __shared__ float red[4][72];
    const int lane = tid & 63, wave = tid >> 6;
    #pragma unroll
    for (int d = 0; d < 9; ++d) {
        #pragma unroll
        for (int e = 0; e < 8; ++e) {
            float v = acc[d][e];
            #pragma unroll
            for (int off = 32; off > 0; off >>= 1) v += __shfl_down(v, off, 64);
            if (lane == 0) red[wave][d * 8 + e] = v;
        }
    }
    __syncthreads();
    if (tid < 72) {
        float v = red[0][tid] + red[1][tid] + red[2][tid] + red[3][tid];
        vk[(size_t)bh * 72 + tid] = v;
    }
}

// ---- attn: head-chunk-transposed write over dead v-rows ----
__global__ __launch_bounds__(256) void attn_out_kernel(
    bf16* __restrict__ qkv, bf16* __restrict__ agg,
    const float* __restrict__ vk)
{
    const int b = blockIdx.z;
    const int h = blockIdx.y;
    const int n = blockIdx.x * 256 + threadIdx.x;
    bf16* base = (h < 64)
        ? (qkv + ((size_t)b * 1536 + h * 24) * 4096)
        : (agg + ((size_t)b * 1536 + (h - 64) * 24) * 4096);

    __shared__ float s_vk[72];
    if (threadIdx.x < 72)
        s_vk[threadIdx.x] = vk[((size_t)b * 128 + h) * 72 + threadIdx.x];
    __syncthreads();

    float q[8];
    #pragma unroll
    for (int e = 0; e < 8; ++e) q[e] = fmaxf(b2f(base[(size_t)e * 4096 + n]), 0.f);

    float o[9];
    #pragma unroll
    for (int d = 0; d < 9; ++d) {
        float s = 0.f;
        #pragma unroll
        for (int e = 0; e < 8; ++e) s += s_vk[d * 8 + e] * q[e];
        o[d] = s;
    }
    const float denom = o[8] + 1e-15f;

    union { bf16 hv[8]; uint4 u; } pk;
    #pragma unroll
    for (int d = 0; d < 8; ++d) pk.hv[d] = f2b(o[d] / denom);
    *(uint4*)((char*)(base + (size_t)16 * 4096) + (size_t)n * 16) = pk.u;
}

extern "C" void kernel_launch(void* const* d_in, const int* in_sizes, int n_in,
                              void* d_out, int out_size, void* d_ws, size_t ws_size,
                              hipStream_t stream) {
    const float* x      = (const float*)d_in[0];
    const float* w_qkv  = (const float*)d_in[1];
    const float* w_dw   = (const float*)d_in[2];
    const float* w_pw   = (const float*)d_in[3];
    const float* w_proj = (const float*)d_in[4];

    char* ws = (char*)d_ws;
    bf16* w_qkv_bf  = (bf16*)ws;
    bf16* w_proj_bf = (bf16*)(ws + 1572864);
    float* vkbf     = (float*)(ws + 1572864 + 1048576);
    bf16* x_t       = (bf16*)(ws + 1572864 + 1048576 + 147456);
    bf16* qkv       = x_t + (size_t)4 * 4096 * 512;
    bf16* agg       = qkv + (size_t)4 * 1536 * 4096;

    convert_kernel<<<3072, 256, 0, stream>>>(w_qkv, w_qkv_bf, 786432);
    convert_kernel<<<2048, 256, 0, stream>>>(w_proj, w_proj_bf, 524288);
    transpose_x_kernel<<<dim3(128, 16, 4), 256, 0, stream>>>(x, x_t);

    mfma_gemm_kernel<false><<<dim3(32, 12, 4), 256, 0, stream>>>(
        w_qkv_bf, x_t, nullptr, nullptr, qkv, 1536, 512);

    dwpw_kernel<<<dim3(1, 2, 768), 256, 0, stream>>>(qkv, w_dw, w_pw, agg);

    vk_kernel<<<dim3(512), 256, 0, stream>>>(qkv, agg, vkbf);

    attn_out_kernel<<<dim3(16, 128, 4), 256, 0, stream>>>(qkv, agg, vkbf);

    mfma_gemm_kernel<true><<<dim3(32, 4, 4), 256, 0, stream>>>(
        w_proj_bf, qkv, agg, x, d_out, 512, 1024);
}

// Round 7
// 328.572 us; speedup vs baseline: 1.0611x; 1.0611x over previous
//
#include <hip/hip_runtime.h>
#include <hip/hip_bf16.h>
#include <cstdint>
#include <cstddef>

// Shapes (fixed): B=4, C=512, H=W=64, N=4096, td=512. Inputs/outputs fp32.
// Compute in bf16 MFMA (GEMMs) / fp32 VALU (convs, attention).
//
// ws layout (bytes; total ~114.6 MiB):
//   w_qkv_bf  1,572,864 | w_proj_bf 1,048,576 | vk 147,456 |
//   x_t (4,4096,512) bf16 16,777,216 | qkv 50,331,648 | agg 50,331,648
//
// attn is stored head-chunk-transposed over the dead v-rows of qkv/agg.

typedef __hip_bfloat16 bf16;
typedef __attribute__((ext_vector_type(8))) short short8;
typedef __attribute__((ext_vector_type(4))) float f32x4;

__device__ __forceinline__ float b2f(bf16 v) { return __bfloat162float(v); }
__device__ __forceinline__ bf16 f2b(float v) { return __float2bfloat16(v); }

__device__ __forceinline__ void async16(void* lds_base, const void* gaddr) {
    __builtin_amdgcn_global_load_lds(
        (const __attribute__((address_space(1))) unsigned int*)gaddr,
        (__attribute__((address_space(3))) unsigned int*)lds_base,
        16, 0, 0);
}

// ---- weight fp32 -> bf16 ----
__global__ __launch_bounds__(256) void convert_kernel(
    const float* __restrict__ src, bf16* __restrict__ dst, int n)
{
    int i = blockIdx.x * 256 + threadIdx.x;
    if (i < n) dst[i] = f2b(src[i]);
}

// ---- x (4,512,4096) fp32 -> x_t (4,4096,512) bf16 ----
__global__ __launch_bounds__(256) void transpose_x_kernel(
    const float* __restrict__ x, bf16* __restrict__ x_t)
{
    __shared__ bf16 tile[32][33];
    const int b = blockIdx.z;
    const int c0 = blockIdx.y * 32;
    const int n0 = blockIdx.x * 32;
    const int tx = threadIdx.x & 31, ty = threadIdx.x >> 5;  // 32x8
    #pragma unroll
    for (int i = 0; i < 32; i += 8)
        tile[ty + i][tx] = f2b(x[((size_t)b * 512 + c0 + ty + i) * 4096 + n0 + tx]);
    __syncthreads();
    #pragma unroll
    for (int i = 0; i < 32; i += 8)
        x_t[((size_t)b * 4096 + n0 + ty + i) * 512 + c0 + tx] = tile[tx][ty + i];
}

// ---- MFMA GEMM, m97 structure: 128x128 tile, BK=32, 4 waves, 64x64/wave ----
template <bool PROJ>
__global__ __launch_bounds__(256) void mfma_gemm_kernel(
    const bf16* __restrict__ A, const bf16* __restrict__ xt_or_qkv,
    const bf16* __restrict__ agg, const float* __restrict__ X,
    void* __restrict__ Cout, int M, int K)
{
    constexpr int N = 4096;
    const int b = blockIdx.z;
    const int m_blk = blockIdx.y * 128;
    const int n_blk = blockIdx.x * 128;

    __shared__ short As[128 * 32];
    __shared__ short Bs[128 * 32];

    const int tid = threadIdx.x;
    const int lane = tid & 63, wave = tid >> 6;
    const int wm = (wave >> 1) * 64, wn = (wave & 1) * 64;
    const int fm = lane & 15, fq = lane >> 4;

    f32x4 acc[4][4] = {};

    const short* Ag = (const short*)A;
    const short* Btg = PROJ ? nullptr
        : (const short*)(xt_or_qkv + (size_t)b * N * 512);

    for (int k0 = 0; k0 < K; k0 += 32) {
        #pragma unroll
        for (int t0 = 0; t0 < 2; ++t0) {
            int t = wave + t0 * 4;
            int row = m_blk + t * 16 + (lane >> 2);
            int col = k0 + (lane & 3) * 8;
            async16(&As[t * 512], Ag + (size_t)row * K + col);
        }
        #pragma unroll
        for (int t0 = 0; t0 < 2; ++t0) {
            int t = wave + t0 * 4;
            int n = n_blk + t * 16 + (lane >> 2);
            if (!PROJ) {
                int col = k0 + (lane & 3) * 8;
                async16(&Bs[t * 512], Btg + (size_t)n * 512 + col);
            } else {
                int h = (k0 >> 3) + (lane & 3);
                const bf16* chunk = (h < 64 ? xt_or_qkv : agg) +
                    ((size_t)b * 1536 + (size_t)(h & 63) * 24 + 16) * 4096;
                async16(&Bs[t * 512], chunk + (size_t)n * 8);
            }
        }
        __syncthreads();

        short8 af[4], bfv[4];
        #pragma unroll
        for (int i = 0; i < 4; ++i)
            af[i] = *(const short8*)&As[(wm + i * 16 + fm) * 32 + fq * 8];
        #pragma unroll
        for (int j = 0; j < 4; ++j)
            bfv[j] = *(const short8*)&Bs[(wn + j * 16 + fm) * 32 + fq * 8];
        #pragma unroll
        for (int i = 0; i < 4; ++i)
            #pragma unroll
            for (int j = 0; j < 4; ++j)
                acc[i][j] = __builtin_amdgcn_mfma_f32_16x16x32_bf16(
                    af[i], bfv[j], acc[i][j], 0, 0, 0);
        __syncthreads();
    }

    if (!PROJ) {
        bf16* Cb = (bf16*)Cout + (size_t)b * M * N;
        #pragma unroll
        for (int i = 0; i < 4; ++i)
            #pragma unroll
            for (int j = 0; j < 4; ++j) {
                int n = n_blk + wn + j * 16 + fm;
                #pragma unroll
                for (int r = 0; r < 4; ++r) {
                    int m = m_blk + wm + i * 16 + fq * 4 + r;
                    Cb[(size_t)m * N + n] = f2b(acc[i][j][r]);
                }
            }
    } else {
        float* Ob = (float*)Cout + (size_t)b * M * N;
        const float* Xb = X + (size_t)b * M * N;
        #pragma unroll
        for (int i = 0; i < 4; ++i)
            #pragma unroll
            for (int j = 0; j < 4; ++j) {
                int n = n_blk + wn + j * 16 + fm;
                #pragma unroll
                for (int r = 0; r < 4; ++r) {
                    int m = m_blk + wm + i * 16 + fq * 4 + r;
                    size_t off = (size_t)m * N + n;
                    Ob[off] = acc[i][j][r] + Xb[off];
                }
            }
    }
}

// ---- fused depthwise 5x5 (pad 2) + grouped pointwise (8->8), v3 ----
// No data LDS: lane = column (64 wide), x-halo via wave shuffles, y-halo via
// per-row predicated loads. One wave = 8-row x 64-col strip, all 8 channels.
__global__ __launch_bounds__(256) void dwpw_kernel(
    const bf16* __restrict__ qkv, const float* __restrict__ w_dw,
    const float* __restrict__ w_pw, bf16* __restrict__ agg)
{
    const int bg = blockIdx.z;       // 0..767
    const int b = bg / 192;
    const int g = bg % 192;

    __shared__ float s_wdw[8][25];
    __shared__ float s_wpw[8][8];    // [o][i]

    const int tid = threadIdx.x;
    const int lane = tid & 63, wave = tid >> 6;

    if (tid < 200) {
        int c = tid / 25, k = tid % 25;
        s_wdw[c][k] = w_dw[(size_t)(g * 8 + c) * 25 + k];
    }
    if (tid < 64)
        s_wpw[tid >> 3][tid & 7] = w_pw[(size_t)(g * 8 + (tid >> 3)) * 8 + (tid & 7)];
    __syncthreads();

    const int r0 = (blockIdx.y * 4 + wave) * 8;   // output rows r0..r0+7
    const size_t chan_base = ((size_t)b * 1536 + g * 8) * 4096;

    float outv[8][8] = {};   // [out_ch][row]

    for (int c = 0; c < 8; ++c) {
        float wr[25];
        #pragma unroll
        for (int k = 0; k < 25; ++k) wr[k] = s_wdw[c][k];
        const bf16* src = qkv + chan_base + (size_t)c * 4096;

        float dwv[8] = {};
        #pragma unroll
        for (int ir = 0; ir < 12; ++ir) {        // input rows r0-2 .. r0+9
            int y = r0 + ir - 2;
            float v2 = (y >= 0 && y < 64) ? b2f(src[y * 64 + lane]) : 0.f;
            float v0 = __shfl_up(v2, 2, 64);   if (lane < 2)  v0 = 0.f;
            float v1 = __shfl_up(v2, 1, 64);   if (lane < 1)  v1 = 0.f;
            float v3 = __shfl_down(v2, 1, 64); if (lane > 62) v3 = 0.f;
            float v4 = __shfl_down(v2, 2, 64); if (lane > 61) v4 = 0.f;
            #pragma unroll
            for (int i = 0; i < 5; ++i) {
                int o = ir - i;                  // compile-time constant
                if (o >= 0 && o < 8)
                    dwv[o] += wr[i * 5 + 0] * v0 + wr[i * 5 + 1] * v1 +
                              wr[i * 5 + 2] * v2 + wr[i * 5 + 3] * v3 +
                              wr[i * 5 + 4] * v4;
            }
        }
        #pragma unroll
        for (int o = 0; o < 8; ++o) {
            float wp = s_wpw[o][c];
            #pragma unroll
            for (int r = 0; r < 8; ++r)
                outv[o][r] += dwv[r] * wp;
        }
    }

    #pragma unroll
    for (int o = 0; o < 8; ++o) {
        bf16* dst = agg + chan_base + (size_t)o * 4096;
        #pragma unroll
        for (int r = 0; r < 8; ++r)
            dst[(size_t)(r0 + r) * 64 + lane] = f2b(outv[o][r]);
    }
}

// ---- vk[bh,d,e] = sum_n v[d,n]*relu(k[e,n]); row d=8 = sum relu(k) ----
__global__ __launch_bounds__(256) void vk_kernel(
    const bf16* __restrict__ qkv, const bf16* __restrict__ agg,
    float* __restrict__ vk)
{
    const int bh = blockIdx.x;   // 0..511
    const int b = bh >> 7;
    const int h = bh & 127;
    const bf16* base = (h < 64)
        ? (qkv + ((size_t)b * 1536 + h * 24) * 4096)
        : (agg + ((size_t)b * 1536 + (h - 64) * 24) * 4096);

    const int tid = threadIdx.x;
    float acc[9][8] = {};

    for (int n = tid; n < 4096; n += 256) {
        float kv[8], vv[8];
        #pragma unroll
        for (int e = 0; e < 8; ++e) kv[e] = fmaxf(b2f(base[(size_t)(8 + e) * 4096 + n]), 0.f);
        #pragma unroll
        for (int d = 0; d < 8; ++d) vv[d] = b2f(base[(size_t)(16 + d) * 4096 + n]);
        #pragma unroll
        for (int d = 0; d < 8; ++d)
            #pragma unroll
            for (int e = 0; e < 8; ++e)
                acc[d][e] += vv[d] * kv[e];
        #pragma unroll
        for (int e = 0; e < 8; ++e) acc[8][e] += kv[e];
    }

    __shared__ float red[4][72];
    const int lane = tid & 63, wave = tid >> 6;
    #pragma unroll
    for (int d = 0; d < 9; ++d) {
        #pragma unroll
        for (int e = 0; e < 8; ++e) {
            float v = acc[d][e];
            #pragma unroll
            for (int off = 32; off > 0; off >>= 1) v += __shfl_down(v, off, 64);
            if (lane == 0) red[wave][d * 8 + e] = v;
        }
    }
    __syncthreads();
    if (tid < 72) {
        float v = red[0][tid] + red[1][tid] + red[2][tid] + red[3][tid];
        vk[(size_t)bh * 72 + tid] = v;
    }
}

// ---- attn: head-chunk-transposed write over dead v-rows ----
__global__ __launch_bounds__(256) void attn_out_kernel(
    bf16* __restrict__ qkv, bf16* __restrict__ agg,
    const float* __restrict__ vk)
{
    const int b = blockIdx.z;
    const int h = blockIdx.y;
    const int n = blockIdx.x * 256 + threadIdx.x;
    bf16* base = (h < 64)
        ? (qkv + ((size_t)b * 1536 + h * 24) * 4096)
        : (agg + ((size_t)b * 1536 + (h - 64) * 24) * 4096);

    __shared__ float s_vk[72];
    if (threadIdx.x < 72)
        s_vk[threadIdx.x] = vk[((size_t)b * 128 + h) * 72 + threadIdx.x];
    __syncthreads();

    float q[8];
    #pragma unroll
    for (int e = 0; e < 8; ++e) q[e] = fmaxf(b2f(base[(size_t)e * 4096 + n]), 0.f);

    float o[9];
    #pragma unroll
    for (int d = 0; d < 9; ++d) {
        float s = 0.f;
        #pragma unroll
        for (int e = 0; e < 8; ++e) s += s_vk[d * 8 + e] * q[e];
        o[d] = s;
    }
    const float denom = o[8] + 1e-15f;

    union { bf16 hv[8]; uint4 u; } pk;
    #pragma unroll
    for (int d = 0; d < 8; ++d) pk.hv[d] = f2b(o[d] / denom);
    *(uint4*)((char*)(base + (size_t)16 * 4096) + (size_t)n * 16) = pk.u;
}

extern "C" void kernel_launch(void* const* d_in, const int* in_sizes, int n_in,
                              void* d_out, int out_size, void* d_ws, size_t ws_size,
                              hipStream_t stream) {
    const float* x      = (const float*)d_in[0];
    const float* w_qkv  = (const float*)d_in[1];
    const float* w_dw   = (const float*)d_in[2];
    const float* w_pw   = (const float*)d_in[3];
    const float* w_proj = (const float*)d_in[4];

    char* ws = (char*)d_ws;
    bf16* w_qkv_bf  = (bf16*)ws;
    bf16* w_proj_bf = (bf16*)(ws + 1572864);
    float* vkbf     = (float*)(ws + 1572864 + 1048576);
    bf16* x_t       = (bf16*)(ws + 1572864 + 1048576 + 147456);
    bf16* qkv       = x_t + (size_t)4 * 4096 * 512;
    bf16* agg       = qkv + (size_t)4 * 1536 * 4096;

    convert_kernel<<<3072, 256, 0, stream>>>(w_qkv, w_qkv_bf, 786432);
    convert_kernel<<<2048, 256, 0, stream>>>(w_proj, w_proj_bf, 524288);
    transpose_x_kernel<<<dim3(128, 16, 4), 256, 0, stream>>>(x, x_t);

    mfma_gemm_kernel<false><<<dim3(32, 12, 4), 256, 0, stream>>>(
        w_qkv_bf, x_t, nullptr, nullptr, qkv, 1536, 512);

    dwpw_kernel<<<dim3(1, 2, 768), 256, 0, stream>>>(qkv, w_dw, w_pw, agg);

    vk_kernel<<<dim3(512), 256, 0, stream>>>(qkv, agg, vkbf);

    attn_out_kernel<<<dim3(16, 128, 4), 256, 0, stream>>>(qkv, agg, vkbf);

    mfma_gemm_kernel<true><<<dim3(32, 4, 4), 256, 0, stream>>>(
        w_proj_bf, qkv, agg, x, d_out, 512, 1024);
}